// Round 6
// baseline (387.303 us; speedup 1.0000x reference)
//
#include <hip/hip_runtime.h>
#include <math.h>
#include <type_traits>

#define N_NODES 50000
#define N_EDGES 800000
#define DIM 96
#define BCH 12                    // 16-byte chunks per bf16 row (96 shorts)
#define SCAN_BLK 256
#define NBLK ((N_NODES + SCAN_BLK - 1) / SCAN_BLK)   // 196

// ---- bf16 helpers (RNE) ----
__device__ __forceinline__ unsigned short f2bf(float f) {
    unsigned int u = __float_as_uint(f);
    u += 0x7FFFu + ((u >> 16) & 1u);
    return (unsigned short)(u >> 16);
}
__device__ __forceinline__ unsigned int pack2bf(float lo, float hi) {
    return (unsigned int)f2bf(lo) | ((unsigned int)f2bf(hi) << 16);
}
__device__ __forceinline__ float bflo(unsigned int u) { return __uint_as_float(u << 16); }
__device__ __forceinline__ float bfhi(unsigned int u) { return __uint_as_float(u & 0xFFFF0000u); }

__device__ __forceinline__ float fast_tanh(float x) {
    float ax = fabsf(x);
    float t = __expf(-2.0f * ax);
    float r = (1.0f - t) / (1.0f + t);
    return copysignf(r, x);
}

// ---------------- linked-list CSR build ----------------

__global__ void link_edges(const int* __restrict__ dst, int* __restrict__ head,
                           int* __restrict__ nxt) {
    int e = blockIdx.x * blockDim.x + threadIdx.x;
    if (e >= N_EDGES) return;
    int old = atomicExch(&head[dst[e]], e);
    nxt[e] = old;
}

__global__ void walk_count_partials(const int* __restrict__ head, const int* __restrict__ nxt,
                                    int* __restrict__ deg, float* __restrict__ norm,
                                    int* __restrict__ partials) {
    int b = blockIdx.x, t = threadIdx.x;
    int n = b * SCAN_BLK + t;
    int cnt = 0;
    if (n < N_NODES) {
        int p = head[n];
        while (p >= 0) { ++cnt; p = nxt[p]; }
        deg[n] = cnt;
        norm[n] = rsqrtf(fmaxf((float)cnt, 1.0f));
    }
    int v = cnt;
#pragma unroll
    for (int off = 32; off > 0; off >>= 1) v += __shfl_down(v, off, 64);
    __shared__ int ws[4];
    if ((t & 63) == 0) ws[t >> 6] = v;
    __syncthreads();
    if (t == 0) partials[b] = ws[0] + ws[1] + ws[2] + ws[3];
}

__global__ void scan_partials(const int* __restrict__ partials, int* __restrict__ pprefix) {
    __shared__ int sm[SCAN_BLK];
    int t = threadIdx.x;
    int v = (t < NBLK) ? partials[t] : 0;
    sm[t] = v;
    __syncthreads();
    for (int off = 1; off < SCAN_BLK; off <<= 1) {
        int u = (t >= off) ? sm[t - off] : 0;
        __syncthreads();
        sm[t] += u;
        __syncthreads();
    }
    if (t < NBLK) pprefix[t] = sm[t] - v;
}

__global__ void scan_compact(const int* __restrict__ deg, const int* __restrict__ pprefix,
                             const int* __restrict__ head, const int* __restrict__ nxt,
                             const int* __restrict__ src, const float* __restrict__ factor,
                             int* __restrict__ offs, int2* __restrict__ entries) {
    __shared__ int sm[SCAN_BLK];
    int b = blockIdx.x, t = threadIdx.x;
    int idx = b * SCAN_BLK + t;
    int v = (idx < N_NODES) ? deg[idx] : 0;
    sm[t] = v;
    __syncthreads();
    for (int off = 1; off < SCAN_BLK; off <<= 1) {
        int u = (t >= off) ? sm[t - off] : 0;
        __syncthreads();
        sm[t] += u;
        __syncthreads();
    }
    if (idx < N_NODES) {
        int o = pprefix[b] + sm[t] - v;
        offs[idx] = o;
        int p = head[idx];
        while (p >= 0) {
            entries[o++] = make_int2(src[p], __float_as_int(factor[p]));
            p = nxt[p];
        }
    }
    if (b == 0 && t == 0) offs[N_NODES] = N_EDGES;
}

// ---------------- LDS-tiled GEMM -> bf16 out ----------------
// out[n][j] = bf16((dot(X[n,:],W[j,:]) + b[j]) * norm[n])

#define MT 64
#define XS_SH 104     // shorts per Xs row (208 B: keeps 16-B alignment, row%8==0 words)
#define WS_ST 100     // floats per Ws row (400 B: 16-B aligned b128 reads)

template <typename T>
__global__ void gemm_tiled(const T* __restrict__ X, const float* __restrict__ W,
                           const float* __restrict__ b, const float* __restrict__ norm,
                           unsigned short* __restrict__ out) {
    __shared__ unsigned short Xs[MT * XS_SH];   // 13.3 KB (bf16 tile)
    __shared__ float Ws[DIM * WS_ST];           // 38.4 KB
    int tid = threadIdx.x;
    int nbase = blockIdx.x * MT;

    if constexpr (std::is_same_v<T, float>) {
        // 64 rows x 24 float4 chunks, convert fp32 -> bf16 while staging
#pragma unroll
        for (int it = 0; it < 6; ++it) {
            int idx = tid + 256 * it;
            int row = idx / 24, c = idx % 24;
            int n = nbase + row;
            float4 v = make_float4(0.f, 0.f, 0.f, 0.f);
            if (n < N_NODES) v = ((const float4*)(X + (size_t)n * DIM))[c];
            *((uint2*)&Xs[row * XS_SH + c * 4]) = make_uint2(pack2bf(v.x, v.y), pack2bf(v.z, v.w));
        }
    } else {
        // bf16 input: 64 rows x 12 uint4 chunks, straight copy
#pragma unroll
        for (int it = 0; it < 3; ++it) {
            int idx = tid + 256 * it;
            int row = idx / 12, c = idx % 12;
            int n = nbase + row;
            uint4 v = make_uint4(0, 0, 0, 0);
            if (n < N_NODES) v = ((const uint4*)(X + (size_t)n * DIM))[c];
            *((uint4*)&Xs[row * XS_SH + c * 8]) = v;
        }
    }
#pragma unroll
    for (int it = 0; it < 9; ++it) {
        int idx = tid + 256 * it;
        int row = idx / 24, c = idx % 24;
        *((float4*)&Ws[row * WS_ST + c * 4]) = ((const float4*)(W + (size_t)row * DIM))[c];
    }
    __syncthreads();

    int g = tid & 15;   // col group: j = g*6 + jj
    int r = tid >> 4;   // node group: n = r*4 + i
    float acc[4][6];
#pragma unroll
    for (int i = 0; i < 4; ++i)
#pragma unroll
        for (int jj = 0; jj < 6; ++jj) acc[i][jj] = 0.f;

#pragma unroll 4
    for (int k4 = 0; k4 < 24; ++k4) {
        float xv[4][4];
#pragma unroll
        for (int i = 0; i < 4; ++i) {
            uint2 xw = *(const uint2*)&Xs[(r * 4 + i) * XS_SH + k4 * 4];
            xv[i][0] = bflo(xw.x); xv[i][1] = bfhi(xw.x);
            xv[i][2] = bflo(xw.y); xv[i][3] = bfhi(xw.y);
        }
        float4 wv[6];
#pragma unroll
        for (int jj = 0; jj < 6; ++jj)
            wv[jj] = *(const float4*)&Ws[(g * 6 + jj) * WS_ST + k4 * 4];
#pragma unroll
        for (int i = 0; i < 4; ++i)
#pragma unroll
            for (int jj = 0; jj < 6; ++jj)
                acc[i][jj] += xv[i][0] * wv[jj].x + xv[i][1] * wv[jj].y +
                              xv[i][2] * wv[jj].z + xv[i][3] * wv[jj].w;
    }

#pragma unroll
    for (int i = 0; i < 4; ++i) {
        int n = nbase + r * 4 + i;
        if (n < N_NODES) {
            float nm = norm[n];
            float v0 = (acc[i][0] + b[g * 6 + 0]) * nm;
            float v1 = (acc[i][1] + b[g * 6 + 1]) * nm;
            float v2 = (acc[i][2] + b[g * 6 + 2]) * nm;
            float v3 = (acc[i][3] + b[g * 6 + 3]) * nm;
            float v4 = (acc[i][4] + b[g * 6 + 4]) * nm;
            float v5 = (acc[i][5] + b[g * 6 + 5]) * nm;
            unsigned int* op = (unsigned int*)(out + (size_t)n * DIM + g * 6);
            op[0] = pack2bf(v0, v1);
            op[1] = pack2bf(v2, v3);
            op[2] = pack2bf(v4, v5);
        }
    }
}

// ---------------- gather aggregation over bf16 feat ----------------

template <bool DO_TANH>
__global__ void gather_agg_bf16(const unsigned short* __restrict__ feat,
                                const int* __restrict__ offs,
                                const int2* __restrict__ entries,
                                unsigned short* __restrict__ out) {
    int idx = blockIdx.x * blockDim.x + threadIdx.x;
    if (idx >= N_NODES * BCH) return;
    int n = idx / BCH;
    int c = idx - n * BCH;
    int beg = offs[n], end = offs[n + 1];
    float a0[8], a1[8];
#pragma unroll
    for (int i = 0; i < 8; ++i) { a0[i] = 0.f; a1[i] = 0.f; }
    int p = beg;
    for (; p + 1 < end; p += 2) {
        int2 e0 = entries[p];
        int2 e1 = entries[p + 1];
        uint4 v0 = *((const uint4*)(feat + (size_t)e0.x * DIM) + c);
        uint4 v1 = *((const uint4*)(feat + (size_t)e1.x * DIM) + c);
        float f0 = __int_as_float(e0.y);
        float f1 = __int_as_float(e1.y);
        a0[0] += bflo(v0.x) * f0; a0[1] += bfhi(v0.x) * f0;
        a0[2] += bflo(v0.y) * f0; a0[3] += bfhi(v0.y) * f0;
        a0[4] += bflo(v0.z) * f0; a0[5] += bfhi(v0.z) * f0;
        a0[6] += bflo(v0.w) * f0; a0[7] += bfhi(v0.w) * f0;
        a1[0] += bflo(v1.x) * f1; a1[1] += bfhi(v1.x) * f1;
        a1[2] += bflo(v1.y) * f1; a1[3] += bfhi(v1.y) * f1;
        a1[4] += bflo(v1.z) * f1; a1[5] += bfhi(v1.z) * f1;
        a1[6] += bflo(v1.w) * f1; a1[7] += bfhi(v1.w) * f1;
    }
    if (p < end) {
        int2 e0 = entries[p];
        uint4 v0 = *((const uint4*)(feat + (size_t)e0.x * DIM) + c);
        float f0 = __int_as_float(e0.y);
        a0[0] += bflo(v0.x) * f0; a0[1] += bfhi(v0.x) * f0;
        a0[2] += bflo(v0.y) * f0; a0[3] += bfhi(v0.y) * f0;
        a0[4] += bflo(v0.z) * f0; a0[5] += bfhi(v0.z) * f0;
        a0[6] += bflo(v0.w) * f0; a0[7] += bfhi(v0.w) * f0;
    }
#pragma unroll
    for (int i = 0; i < 8; ++i) a0[i] += a1[i];
    if (DO_TANH) {
#pragma unroll
        for (int i = 0; i < 8; ++i) a0[i] = fast_tanh(a0[i]);
    }
    uint4 o;
    o.x = pack2bf(a0[0], a0[1]);
    o.y = pack2bf(a0[2], a0[3]);
    o.z = pack2bf(a0[4], a0[5]);
    o.w = pack2bf(a0[6], a0[7]);
    ((uint4*)out)[idx] = o;
}

// ---------------- pooling ----------------

#define CS_T (416 * 192)   // 79872 threads, multiple of 48 -> uint column-pair invariant
__global__ void tanh_colsum_bf16(const unsigned int* __restrict__ agg, float* __restrict__ pooled) {
    int gtid = blockIdx.x * blockDim.x + threadIdx.x;
    float s0 = 0.f, s1 = 0.f;
    for (int i = gtid; i < N_NODES * DIM / 2; i += CS_T) {
        unsigned int u = agg[i];
        s0 += fast_tanh(bflo(u));
        s1 += fast_tanh(bfhi(u));
    }
    int cp = (gtid % 48) * 2;
    atomicAdd(&pooled[cp], s0);
    atomicAdd(&pooled[cp + 1], s1);
}

__global__ void final_tanh(const float* __restrict__ pooled, float* __restrict__ out) {
    int j = threadIdx.x;
    if (j < DIM) out[j] = tanhf(pooled[j] * (1.0f / N_NODES));
}

// ---------------- launch ----------------

extern "C" void kernel_launch(void* const* d_in, const int* in_sizes, int n_in,
                              void* d_out, int out_size, void* d_ws, size_t ws_size,
                              hipStream_t stream) {
    const float* inputs = (const float*)d_in[0];
    const float* W1     = (const float*)d_in[1];
    const float* b1     = (const float*)d_in[2];
    const float* W2     = (const float*)d_in[3];
    const float* b2     = (const float*)d_in[4];
    const float* factor = (const float*)d_in[5];
    const int*   src    = (const int*)d_in[6];
    const int*   dst    = (const int*)d_in[7];
    float* out = (float*)d_out;

    char* ws = (char*)d_ws;
    int*            head     = (int*)(ws + 0);              // 200 KB
    int*            nxt      = (int*)(ws + 262144);         // 3.2 MB
    int*            deg      = (int*)(ws + 3670016);        // 200 KB
    int*            offs     = (int*)(ws + 3932160);        // 200 KB (+1)
    float*          norm     = (float*)(ws + 4194304);      // 200 KB
    int*            partials = (int*)(ws + 4456448);        // 1 KB
    int*            pprefix  = (int*)(ws + 4458496);        // 1 KB
    int2*           entries  = (int2*)(ws + 4718592);       // 6.4 MB
    unsigned short* bufA     = (unsigned short*)(ws + 11534336);  // 9.6 MB bf16 feat
    unsigned short* bufB     = (unsigned short*)(ws + 21364736);  // 9.6 MB bf16 feat
    float*          pooled   = (float*)(ws + 31195136);     // 384 B

    // linked-list CSR build
    hipMemsetAsync(head, 0xFF, N_NODES * sizeof(int), stream);
    link_edges<<<(N_EDGES + 255) / 256, 256, 0, stream>>>(dst, head, nxt);
    walk_count_partials<<<NBLK, SCAN_BLK, 0, stream>>>(head, nxt, deg, norm, partials);
    scan_partials<<<1, SCAN_BLK, 0, stream>>>(partials, pprefix);
    scan_compact<<<NBLK, SCAN_BLK, 0, stream>>>(deg, pprefix, head, nxt, src, factor,
                                                offs, entries);

    const int GEMM_BLOCKS = (N_NODES + MT - 1) / MT;
    const int AGG_THREADS = N_NODES * BCH;

    // layer 1
    gemm_tiled<float><<<GEMM_BLOCKS, 256, 0, stream>>>(inputs, W1, b1, norm, bufA);
    gather_agg_bf16<true><<<(AGG_THREADS + 255) / 256, 256, 0, stream>>>(bufA, offs, entries, bufB);

    // layer 2
    gemm_tiled<unsigned short><<<GEMM_BLOCKS, 256, 0, stream>>>(bufB, W2, b2, norm, bufA);
    gather_agg_bf16<false><<<(AGG_THREADS + 255) / 256, 256, 0, stream>>>(bufA, offs, entries, bufB);

    // pooled mean + tanh
    hipMemsetAsync(pooled, 0, DIM * sizeof(float), stream);
    tanh_colsum_bf16<<<416, 192, 0, stream>>>((const unsigned int*)bufB, pooled);
    final_tanh<<<1, 128, 0, stream>>>(pooled, out);
}

// Round 7
// 354.702 us; speedup vs baseline: 1.0919x; 1.0919x over previous
//
#include <hip/hip_runtime.h>
#include <math.h>
#include <type_traits>

#define N_NODES 50000
#define N_EDGES 800000
#define DIM 96
#define BCH 12                    // 16-byte chunks per bf16 row (96 shorts)
#define SCAN_BLK 256
#define NBLK ((N_NODES + SCAN_BLK - 1) / SCAN_BLK)    // 196
#define NB_AGG ((N_NODES * BCH + 255) / 256)          // 2344 gather blocks

// ---- bf16 helpers (RNE) ----
__device__ __forceinline__ unsigned short f2bf(float f) {
    unsigned int u = __float_as_uint(f);
    u += 0x7FFFu + ((u >> 16) & 1u);
    return (unsigned short)(u >> 16);
}
__device__ __forceinline__ unsigned int pack2bf(float lo, float hi) {
    return (unsigned int)f2bf(lo) | ((unsigned int)f2bf(hi) << 16);
}
__device__ __forceinline__ float bflo(unsigned int u) { return __uint_as_float(u << 16); }
__device__ __forceinline__ float bfhi(unsigned int u) { return __uint_as_float(u & 0xFFFF0000u); }

__device__ __forceinline__ float fast_tanh(float x) {
    float ax = fabsf(x);
    float t = __expf(-2.0f * ax);
    float r = (1.0f - t) / (1.0f + t);
    return copysignf(r, x);
}

// ---------------- linked-list CSR build ----------------

__global__ void link_edges(const int* __restrict__ dst, int* __restrict__ head,
                           int* __restrict__ nxt) {
    int e = blockIdx.x * blockDim.x + threadIdx.x;
    if (e >= N_EDGES) return;
    int old = atomicExch(&head[dst[e]], e);
    nxt[e] = old;
}

__global__ void walk_count_partials(const int* __restrict__ head, const int* __restrict__ nxt,
                                    int* __restrict__ deg, float* __restrict__ norm,
                                    int* __restrict__ partials) {
    int b = blockIdx.x, t = threadIdx.x;
    int n = b * SCAN_BLK + t;
    int cnt = 0;
    if (n < N_NODES) {
        int p = head[n];
        while (p >= 0) { ++cnt; p = nxt[p]; }
        deg[n] = cnt;
        norm[n] = rsqrtf(fmaxf((float)cnt, 1.0f));
    }
    int v = cnt;
#pragma unroll
    for (int off = 32; off > 0; off >>= 1) v += __shfl_down(v, off, 64);
    __shared__ int ws[4];
    if ((t & 63) == 0) ws[t >> 6] = v;
    __syncthreads();
    if (t == 0) partials[b] = ws[0] + ws[1] + ws[2] + ws[3];
}

__global__ void scan_partials(const int* __restrict__ partials, int* __restrict__ pprefix) {
    __shared__ int sm[SCAN_BLK];
    int t = threadIdx.x;
    int v = (t < NBLK) ? partials[t] : 0;
    sm[t] = v;
    __syncthreads();
    for (int off = 1; off < SCAN_BLK; off <<= 1) {
        int u = (t >= off) ? sm[t - off] : 0;
        __syncthreads();
        sm[t] += u;
        __syncthreads();
    }
    if (t < NBLK) pprefix[t] = sm[t] - v;
}

__global__ void scan_compact(const int* __restrict__ deg, const int* __restrict__ pprefix,
                             const int* __restrict__ head, const int* __restrict__ nxt,
                             const int* __restrict__ src, const float* __restrict__ factor,
                             int* __restrict__ offs, int2* __restrict__ entries) {
    __shared__ int sm[SCAN_BLK];
    int b = blockIdx.x, t = threadIdx.x;
    int idx = b * SCAN_BLK + t;
    int v = (idx < N_NODES) ? deg[idx] : 0;
    sm[t] = v;
    __syncthreads();
    for (int off = 1; off < SCAN_BLK; off <<= 1) {
        int u = (t >= off) ? sm[t - off] : 0;
        __syncthreads();
        sm[t] += u;
        __syncthreads();
    }
    if (idx < N_NODES) {
        int o = pprefix[b] + sm[t] - v;
        offs[idx] = o;
        int p = head[idx];
        while (p >= 0) {
            entries[o++] = make_int2(src[p], __float_as_int(factor[p]));
            p = nxt[p];
        }
    }
    if (b == 0 && t == 0) offs[N_NODES] = N_EDGES;
}

// ---------------- LDS-tiled GEMM -> bf16 out ----------------

#define MT 64
#define XS_SH 104     // shorts per Xs row (208 B: 16-B aligned)
#define WS_ST 100     // floats per Ws row (400 B: 16-B aligned)

template <typename T>
__global__ void gemm_tiled(const T* __restrict__ X, const float* __restrict__ W,
                           const float* __restrict__ b, const float* __restrict__ norm,
                           unsigned short* __restrict__ out) {
    __shared__ unsigned short Xs[MT * XS_SH];   // 13.3 KB
    __shared__ float Ws[DIM * WS_ST];           // 38.4 KB
    int tid = threadIdx.x;
    int nbase = blockIdx.x * MT;

    if constexpr (std::is_same_v<T, float>) {
#pragma unroll
        for (int it = 0; it < 6; ++it) {
            int idx = tid + 256 * it;
            int row = idx / 24, c = idx % 24;
            int n = nbase + row;
            float4 v = make_float4(0.f, 0.f, 0.f, 0.f);
            if (n < N_NODES) v = ((const float4*)(X + (size_t)n * DIM))[c];
            *((uint2*)&Xs[row * XS_SH + c * 4]) = make_uint2(pack2bf(v.x, v.y), pack2bf(v.z, v.w));
        }
    } else {
#pragma unroll
        for (int it = 0; it < 3; ++it) {
            int idx = tid + 256 * it;
            int row = idx / 12, c = idx % 12;
            int n = nbase + row;
            uint4 v = make_uint4(0, 0, 0, 0);
            if (n < N_NODES) v = ((const uint4*)(X + (size_t)n * DIM))[c];
            *((uint4*)&Xs[row * XS_SH + c * 8]) = v;
        }
    }
#pragma unroll
    for (int it = 0; it < 9; ++it) {
        int idx = tid + 256 * it;
        int row = idx / 24, c = idx % 24;
        *((float4*)&Ws[row * WS_ST + c * 4]) = ((const float4*)(W + (size_t)row * DIM))[c];
    }
    __syncthreads();

    int g = tid & 15;   // col group: j = g*6 + jj
    int r = tid >> 4;   // node group: n = r*4 + i
    float acc[4][6];
#pragma unroll
    for (int i = 0; i < 4; ++i)
#pragma unroll
        for (int jj = 0; jj < 6; ++jj) acc[i][jj] = 0.f;

#pragma unroll 4
    for (int k4 = 0; k4 < 24; ++k4) {
        float xv[4][4];
#pragma unroll
        for (int i = 0; i < 4; ++i) {
            uint2 xw = *(const uint2*)&Xs[(r * 4 + i) * XS_SH + k4 * 4];
            xv[i][0] = bflo(xw.x); xv[i][1] = bfhi(xw.x);
            xv[i][2] = bflo(xw.y); xv[i][3] = bfhi(xw.y);
        }
        float4 wv[6];
#pragma unroll
        for (int jj = 0; jj < 6; ++jj)
            wv[jj] = *(const float4*)&Ws[(g * 6 + jj) * WS_ST + k4 * 4];
#pragma unroll
        for (int i = 0; i < 4; ++i)
#pragma unroll
            for (int jj = 0; jj < 6; ++jj)
                acc[i][jj] += xv[i][0] * wv[jj].x + xv[i][1] * wv[jj].y +
                              xv[i][2] * wv[jj].z + xv[i][3] * wv[jj].w;
    }

#pragma unroll
    for (int i = 0; i < 4; ++i) {
        int n = nbase + r * 4 + i;
        if (n < N_NODES) {
            float nm = norm[n];
            float v0 = (acc[i][0] + b[g * 6 + 0]) * nm;
            float v1 = (acc[i][1] + b[g * 6 + 1]) * nm;
            float v2 = (acc[i][2] + b[g * 6 + 2]) * nm;
            float v3 = (acc[i][3] + b[g * 6 + 3]) * nm;
            float v4 = (acc[i][4] + b[g * 6 + 4]) * nm;
            float v5 = (acc[i][5] + b[g * 6 + 5]) * nm;
            unsigned int* op = (unsigned int*)(out + (size_t)n * DIM + g * 6);
            op[0] = pack2bf(v0, v1);
            op[1] = pack2bf(v2, v3);
            op[2] = pack2bf(v4, v5);
        }
    }
}

// ---------------- gather aggregation over bf16 feat ----------------
// POOL=true (layer 2): apply tanh, accumulate into per-block 96-col LDS pool,
// write block partial vector (no feature write, no global atomics).

template <bool DO_TANH, bool POOL>
__global__ void gather_agg_bf16(const unsigned short* __restrict__ feat,
                                const int* __restrict__ offs,
                                const int2* __restrict__ entries,
                                unsigned short* __restrict__ out,
                                float* __restrict__ partials) {
    __shared__ float pool[DIM];
    int tid = threadIdx.x;
    if (POOL) {
        if (tid < DIM) pool[tid] = 0.f;
        __syncthreads();
    }
    int idx = blockIdx.x * blockDim.x + tid;
    bool active = idx < N_NODES * BCH;
    float a0[8];
#pragma unroll
    for (int i = 0; i < 8; ++i) a0[i] = 0.f;
    int c = 0;
    if (active) {
        int n = idx / BCH;
        c = idx - n * BCH;
        int beg = offs[n], end = offs[n + 1];
        float a1[8];
#pragma unroll
        for (int i = 0; i < 8; ++i) a1[i] = 0.f;
        int p = beg;
        for (; p + 1 < end; p += 2) {
            int2 e0 = entries[p];
            int2 e1 = entries[p + 1];
            uint4 v0 = *((const uint4*)(feat + (size_t)e0.x * DIM) + c);
            uint4 v1 = *((const uint4*)(feat + (size_t)e1.x * DIM) + c);
            float f0 = __int_as_float(e0.y);
            float f1 = __int_as_float(e1.y);
            a0[0] += bflo(v0.x) * f0; a0[1] += bfhi(v0.x) * f0;
            a0[2] += bflo(v0.y) * f0; a0[3] += bfhi(v0.y) * f0;
            a0[4] += bflo(v0.z) * f0; a0[5] += bfhi(v0.z) * f0;
            a0[6] += bflo(v0.w) * f0; a0[7] += bfhi(v0.w) * f0;
            a1[0] += bflo(v1.x) * f1; a1[1] += bfhi(v1.x) * f1;
            a1[2] += bflo(v1.y) * f1; a1[3] += bfhi(v1.y) * f1;
            a1[4] += bflo(v1.z) * f1; a1[5] += bfhi(v1.z) * f1;
            a1[6] += bflo(v1.w) * f1; a1[7] += bfhi(v1.w) * f1;
        }
        if (p < end) {
            int2 e0 = entries[p];
            uint4 v0 = *((const uint4*)(feat + (size_t)e0.x * DIM) + c);
            float f0 = __int_as_float(e0.y);
            a0[0] += bflo(v0.x) * f0; a0[1] += bfhi(v0.x) * f0;
            a0[2] += bflo(v0.y) * f0; a0[3] += bfhi(v0.y) * f0;
            a0[4] += bflo(v0.z) * f0; a0[5] += bfhi(v0.z) * f0;
            a0[6] += bflo(v0.w) * f0; a0[7] += bfhi(v0.w) * f0;
        }
#pragma unroll
        for (int i = 0; i < 8; ++i) a0[i] += a1[i];
        if (DO_TANH || POOL) {
#pragma unroll
            for (int i = 0; i < 8; ++i) a0[i] = fast_tanh(a0[i]);
        }
        if (!POOL) {
            uint4 o;
            o.x = pack2bf(a0[0], a0[1]);
            o.y = pack2bf(a0[2], a0[3]);
            o.z = pack2bf(a0[4], a0[5]);
            o.w = pack2bf(a0[6], a0[7]);
            ((uint4*)out)[idx] = o;
        }
    }
    if (POOL) {
        if (active) {
#pragma unroll
            for (int i = 0; i < 8; ++i) atomicAdd(&pool[c * 8 + i], a0[i]);
        }
        __syncthreads();
        if (tid < DIM) partials[(size_t)blockIdx.x * DIM + tid] = pool[tid];
    }
}

// ---------------- final reduce: sum block partials per column, tanh(mean) ----------------

__global__ void reduce_pool(const float* __restrict__ partials, float* __restrict__ out) {
    __shared__ float sm[960];
    int t = threadIdx.x;           // 960 threads: 96 cols x 10 slices
    int col = t % DIM, slice = t / DIM;
    float s = 0.f;
    for (int k = slice; k < NB_AGG; k += 10) s += partials[(size_t)k * DIM + col];
    sm[t] = s;
    __syncthreads();
    if (t < DIM) {
        float tot = 0.f;
#pragma unroll
        for (int i = 0; i < 10; ++i) tot += sm[i * DIM + t];
        out[t] = tanhf(tot * (1.0f / N_NODES));
    }
}

// ---------------- launch ----------------

extern "C" void kernel_launch(void* const* d_in, const int* in_sizes, int n_in,
                              void* d_out, int out_size, void* d_ws, size_t ws_size,
                              hipStream_t stream) {
    const float* inputs = (const float*)d_in[0];
    const float* W1     = (const float*)d_in[1];
    const float* b1     = (const float*)d_in[2];
    const float* W2     = (const float*)d_in[3];
    const float* b2     = (const float*)d_in[4];
    const float* factor = (const float*)d_in[5];
    const int*   src    = (const int*)d_in[6];
    const int*   dst    = (const int*)d_in[7];
    float* out = (float*)d_out;

    char* ws = (char*)d_ws;
    int*            head     = (int*)(ws + 0);              // 200 KB
    int*            nxt      = (int*)(ws + 262144);         // 3.2 MB
    int*            deg      = (int*)(ws + 3670016);        // 200 KB
    int*            offs     = (int*)(ws + 3932160);        // 200 KB (+1)
    float*          norm     = (float*)(ws + 4194304);      // 200 KB
    int*            partials = (int*)(ws + 4456448);        // 1 KB
    int*            pprefix  = (int*)(ws + 4458496);        // 1 KB
    int2*           entries  = (int2*)(ws + 4718592);       // 6.4 MB
    unsigned short* bufA     = (unsigned short*)(ws + 11534336);  // 9.6 MB bf16 feat
    unsigned short* bufB     = (unsigned short*)(ws + 21364736);  // 9.6 MB bf16 feat
    float*          poolpart = (float*)(ws + 31195136);     // 900 KB (NB_AGG x 96)

    // linked-list CSR build
    hipMemsetAsync(head, 0xFF, N_NODES * sizeof(int), stream);
    link_edges<<<(N_EDGES + 255) / 256, 256, 0, stream>>>(dst, head, nxt);
    walk_count_partials<<<NBLK, SCAN_BLK, 0, stream>>>(head, nxt, deg, norm, partials);
    scan_partials<<<1, SCAN_BLK, 0, stream>>>(partials, pprefix);
    scan_compact<<<NBLK, SCAN_BLK, 0, stream>>>(deg, pprefix, head, nxt, src, factor,
                                                offs, entries);

    const int GEMM_BLOCKS = (N_NODES + MT - 1) / MT;

    // layer 1
    gemm_tiled<float><<<GEMM_BLOCKS, 256, 0, stream>>>(inputs, W1, b1, norm, bufA);
    gather_agg_bf16<true, false><<<NB_AGG, 256, 0, stream>>>(bufA, offs, entries, bufB, nullptr);

    // layer 2 (gather fuses tanh + column pooling, no feature write)
    gemm_tiled<unsigned short><<<GEMM_BLOCKS, 256, 0, stream>>>(bufB, W2, b2, norm, bufA);
    gather_agg_bf16<false, true><<<NB_AGG, 256, 0, stream>>>(bufA, offs, entries, nullptr, poolpart);

    // final reduce -> out
    reduce_pool<<<1, 960, 0, stream>>>(poolpart, out);
}

// Round 8
// 300.432 us; speedup vs baseline: 1.2892x; 1.1806x over previous
//
#include <hip/hip_runtime.h>
#include <math.h>
#include <type_traits>

#define N_NODES 50000
#define N_EDGES 800000
#define DIM 96
#define BCH 12                    // 16-byte chunks per bf16 row (96 shorts)
#define SCAN_BLK 256
#define NBLK ((N_NODES + SCAN_BLK - 1) / SCAN_BLK)    // 196
#define NB_AGG ((N_NODES * BCH + 255) / 256)          // 2344 gather blocks
#define R1_ROWS 24
#define R1_BLOCKS ((NB_AGG + R1_ROWS - 1) / R1_ROWS)  // 98

// ---- bf16 helpers (RNE) ----
__device__ __forceinline__ unsigned short f2bf(float f) {
    unsigned int u = __float_as_uint(f);
    u += 0x7FFFu + ((u >> 16) & 1u);
    return (unsigned short)(u >> 16);
}
__device__ __forceinline__ unsigned int pack2bf(float lo, float hi) {
    return (unsigned int)f2bf(lo) | ((unsigned int)f2bf(hi) << 16);
}
__device__ __forceinline__ float bflo(unsigned int u) { return __uint_as_float(u << 16); }
__device__ __forceinline__ float bfhi(unsigned int u) { return __uint_as_float(u & 0xFFFF0000u); }

__device__ __forceinline__ float fast_tanh(float x) {
    float ax = fabsf(x);
    float t = __expf(-2.0f * ax);
    float r = (1.0f - t) / (1.0f + t);
    return copysignf(r, x);
}

// ---------------- linked-list CSR build ----------------

__global__ void link_edges(const int* __restrict__ dst, int* __restrict__ head,
                           int* __restrict__ nxt) {
    int e = blockIdx.x * blockDim.x + threadIdx.x;
    if (e >= N_EDGES) return;
    int old = atomicExch(&head[dst[e]], e);
    nxt[e] = old;
}

__global__ void walk_count_partials(const int* __restrict__ head, const int* __restrict__ nxt,
                                    int* __restrict__ deg, float* __restrict__ norm,
                                    int* __restrict__ partials) {
    int b = blockIdx.x, t = threadIdx.x;
    int n = b * SCAN_BLK + t;
    int cnt = 0;
    if (n < N_NODES) {
        int p = head[n];
        while (p >= 0) { ++cnt; p = nxt[p]; }
        deg[n] = cnt;
        norm[n] = rsqrtf(fmaxf((float)cnt, 1.0f));
    }
    int v = cnt;
#pragma unroll
    for (int off = 32; off > 0; off >>= 1) v += __shfl_down(v, off, 64);
    __shared__ int ws[4];
    if ((t & 63) == 0) ws[t >> 6] = v;
    __syncthreads();
    if (t == 0) partials[b] = ws[0] + ws[1] + ws[2] + ws[3];
}

__global__ void scan_partials(const int* __restrict__ partials, int* __restrict__ pprefix) {
    __shared__ int sm[SCAN_BLK];
    int t = threadIdx.x;
    int v = (t < NBLK) ? partials[t] : 0;
    sm[t] = v;
    __syncthreads();
    for (int off = 1; off < SCAN_BLK; off <<= 1) {
        int u = (t >= off) ? sm[t - off] : 0;
        __syncthreads();
        sm[t] += u;
        __syncthreads();
    }
    if (t < NBLK) pprefix[t] = sm[t] - v;
}

__global__ void scan_compact(const int* __restrict__ deg, const int* __restrict__ pprefix,
                             const int* __restrict__ head, const int* __restrict__ nxt,
                             const int* __restrict__ src, const float* __restrict__ factor,
                             int* __restrict__ offs, int2* __restrict__ entries) {
    __shared__ int sm[SCAN_BLK];
    int b = blockIdx.x, t = threadIdx.x;
    int idx = b * SCAN_BLK + t;
    int v = (idx < N_NODES) ? deg[idx] : 0;
    sm[t] = v;
    __syncthreads();
    for (int off = 1; off < SCAN_BLK; off <<= 1) {
        int u = (t >= off) ? sm[t - off] : 0;
        __syncthreads();
        sm[t] += u;
        __syncthreads();
    }
    if (idx < N_NODES) {
        int o = pprefix[b] + sm[t] - v;
        offs[idx] = o;
        int p = head[idx];
        while (p >= 0) {
            entries[o++] = make_int2(src[p], __float_as_int(factor[p]));
            p = nxt[p];
        }
    }
    if (b == 0 && t == 0) offs[N_NODES] = N_EDGES;
}

// ---------------- LDS-tiled GEMM -> bf16 out ----------------

#define MT 64
#define XS_SH 104     // shorts per Xs row (208 B: 16-B aligned)
#define WS_ST 100     // floats per Ws row (400 B: 16-B aligned)

template <typename T>
__global__ void gemm_tiled(const T* __restrict__ X, const float* __restrict__ W,
                           const float* __restrict__ b, const float* __restrict__ norm,
                           unsigned short* __restrict__ out) {
    __shared__ unsigned short Xs[MT * XS_SH];   // 13.3 KB
    __shared__ float Ws[DIM * WS_ST];           // 38.4 KB
    int tid = threadIdx.x;
    int nbase = blockIdx.x * MT;

    if constexpr (std::is_same_v<T, float>) {
#pragma unroll
        for (int it = 0; it < 6; ++it) {
            int idx = tid + 256 * it;
            int row = idx / 24, c = idx % 24;
            int n = nbase + row;
            float4 v = make_float4(0.f, 0.f, 0.f, 0.f);
            if (n < N_NODES) v = ((const float4*)(X + (size_t)n * DIM))[c];
            *((uint2*)&Xs[row * XS_SH + c * 4]) = make_uint2(pack2bf(v.x, v.y), pack2bf(v.z, v.w));
        }
    } else {
#pragma unroll
        for (int it = 0; it < 3; ++it) {
            int idx = tid + 256 * it;
            int row = idx / 12, c = idx % 12;
            int n = nbase + row;
            uint4 v = make_uint4(0, 0, 0, 0);
            if (n < N_NODES) v = ((const uint4*)(X + (size_t)n * DIM))[c];
            *((uint4*)&Xs[row * XS_SH + c * 8]) = v;
        }
    }
#pragma unroll
    for (int it = 0; it < 9; ++it) {
        int idx = tid + 256 * it;
        int row = idx / 24, c = idx % 24;
        *((float4*)&Ws[row * WS_ST + c * 4]) = ((const float4*)(W + (size_t)row * DIM))[c];
    }
    __syncthreads();

    int g = tid & 15;   // col group: j = g*6 + jj
    int r = tid >> 4;   // node group: n = r*4 + i
    float acc[4][6];
#pragma unroll
    for (int i = 0; i < 4; ++i)
#pragma unroll
        for (int jj = 0; jj < 6; ++jj) acc[i][jj] = 0.f;

#pragma unroll 4
    for (int k4 = 0; k4 < 24; ++k4) {
        float xv[4][4];
#pragma unroll
        for (int i = 0; i < 4; ++i) {
            uint2 xw = *(const uint2*)&Xs[(r * 4 + i) * XS_SH + k4 * 4];
            xv[i][0] = bflo(xw.x); xv[i][1] = bfhi(xw.x);
            xv[i][2] = bflo(xw.y); xv[i][3] = bfhi(xw.y);
        }
        float4 wv[6];
#pragma unroll
        for (int jj = 0; jj < 6; ++jj)
            wv[jj] = *(const float4*)&Ws[(g * 6 + jj) * WS_ST + k4 * 4];
#pragma unroll
        for (int i = 0; i < 4; ++i)
#pragma unroll
            for (int jj = 0; jj < 6; ++jj)
                acc[i][jj] += xv[i][0] * wv[jj].x + xv[i][1] * wv[jj].y +
                              xv[i][2] * wv[jj].z + xv[i][3] * wv[jj].w;
    }

#pragma unroll
    for (int i = 0; i < 4; ++i) {
        int n = nbase + r * 4 + i;
        if (n < N_NODES) {
            float nm = norm[n];
            float v0 = (acc[i][0] + b[g * 6 + 0]) * nm;
            float v1 = (acc[i][1] + b[g * 6 + 1]) * nm;
            float v2 = (acc[i][2] + b[g * 6 + 2]) * nm;
            float v3 = (acc[i][3] + b[g * 6 + 3]) * nm;
            float v4 = (acc[i][4] + b[g * 6 + 4]) * nm;
            float v5 = (acc[i][5] + b[g * 6 + 5]) * nm;
            unsigned int* op = (unsigned int*)(out + (size_t)n * DIM + g * 6);
            op[0] = pack2bf(v0, v1);
            op[1] = pack2bf(v2, v3);
            op[2] = pack2bf(v4, v5);
        }
    }
}

// ---------------- gather aggregation over bf16 feat ----------------
// POOL=true (layer 2): apply tanh, accumulate into per-block 96-col LDS pool,
// write block partial vector (no feature write, no global atomics).

template <bool DO_TANH, bool POOL>
__global__ void gather_agg_bf16(const unsigned short* __restrict__ feat,
                                const int* __restrict__ offs,
                                const int2* __restrict__ entries,
                                unsigned short* __restrict__ out,
                                float* __restrict__ partials) {
    __shared__ float pool[DIM];
    int tid = threadIdx.x;
    if (POOL) {
        if (tid < DIM) pool[tid] = 0.f;
        __syncthreads();
    }
    int idx = blockIdx.x * blockDim.x + tid;
    bool active = idx < N_NODES * BCH;
    float a0[8];
#pragma unroll
    for (int i = 0; i < 8; ++i) a0[i] = 0.f;
    int c = 0;
    if (active) {
        int n = idx / BCH;
        c = idx - n * BCH;
        int beg = offs[n], end = offs[n + 1];
        float a1[8];
#pragma unroll
        for (int i = 0; i < 8; ++i) a1[i] = 0.f;
        int p = beg;
        for (; p + 1 < end; p += 2) {
            int2 e0 = entries[p];
            int2 e1 = entries[p + 1];
            uint4 v0 = *((const uint4*)(feat + (size_t)e0.x * DIM) + c);
            uint4 v1 = *((const uint4*)(feat + (size_t)e1.x * DIM) + c);
            float f0 = __int_as_float(e0.y);
            float f1 = __int_as_float(e1.y);
            a0[0] += bflo(v0.x) * f0; a0[1] += bfhi(v0.x) * f0;
            a0[2] += bflo(v0.y) * f0; a0[3] += bfhi(v0.y) * f0;
            a0[4] += bflo(v0.z) * f0; a0[5] += bfhi(v0.z) * f0;
            a0[6] += bflo(v0.w) * f0; a0[7] += bfhi(v0.w) * f0;
            a1[0] += bflo(v1.x) * f1; a1[1] += bfhi(v1.x) * f1;
            a1[2] += bflo(v1.y) * f1; a1[3] += bfhi(v1.y) * f1;
            a1[4] += bflo(v1.z) * f1; a1[5] += bfhi(v1.z) * f1;
            a1[6] += bflo(v1.w) * f1; a1[7] += bfhi(v1.w) * f1;
        }
        if (p < end) {
            int2 e0 = entries[p];
            uint4 v0 = *((const uint4*)(feat + (size_t)e0.x * DIM) + c);
            float f0 = __int_as_float(e0.y);
            a0[0] += bflo(v0.x) * f0; a0[1] += bfhi(v0.x) * f0;
            a0[2] += bflo(v0.y) * f0; a0[3] += bfhi(v0.y) * f0;
            a0[4] += bflo(v0.z) * f0; a0[5] += bfhi(v0.z) * f0;
            a0[6] += bflo(v0.w) * f0; a0[7] += bfhi(v0.w) * f0;
        }
#pragma unroll
        for (int i = 0; i < 8; ++i) a0[i] += a1[i];
        if (DO_TANH || POOL) {
#pragma unroll
            for (int i = 0; i < 8; ++i) a0[i] = fast_tanh(a0[i]);
        }
        if (!POOL) {
            uint4 o;
            o.x = pack2bf(a0[0], a0[1]);
            o.y = pack2bf(a0[2], a0[3]);
            o.z = pack2bf(a0[4], a0[5]);
            o.w = pack2bf(a0[6], a0[7]);
            ((uint4*)out)[idx] = o;
        }
    }
    if (POOL) {
        if (active) {
#pragma unroll
            for (int i = 0; i < 8; ++i) atomicAdd(&pool[c * 8 + i], a0[i]);
        }
        __syncthreads();
        if (tid < DIM) partials[(size_t)blockIdx.x * DIM + tid] = pool[tid];
    }
}

// ---------------- two-stage pooled reduce ----------------

// stage 1: 98 blocks, each sums a 24-row strip of poolpart (2304 coalesced floats)
__global__ void reduce_stage1(const float* __restrict__ poolpart, float* __restrict__ stage1) {
    __shared__ float pool[DIM];
    int b = blockIdx.x, t = threadIdx.x;
    if (t < DIM) pool[t] = 0.f;
    __syncthreads();
    const int base = b * R1_ROWS * DIM;      // strip start (multiple of 96)
    float loc = 0.f;
    int lastc = -1;
    // accumulate per-element into LDS pool (col of element i is i % 96)
    for (int i = t; i < R1_ROWS * DIM; i += 256) {
        int gi = base + i;
        if (gi < NB_AGG * DIM) {
            int col = i % DIM;
            if (col != lastc) {
                if (lastc >= 0) atomicAdd(&pool[lastc], loc);
                lastc = col; loc = 0.f;
            }
            loc += poolpart[gi];
        }
    }
    if (lastc >= 0) atomicAdd(&pool[lastc], loc);
    __syncthreads();
    if (t < DIM) stage1[b * DIM + t] = pool[t];
}

// stage 2: one block, 960 threads = 96 cols x 10 slices over 98 rows
__global__ void reduce_stage2(const float* __restrict__ stage1, float* __restrict__ out) {
    __shared__ float sm[960];
    int t = threadIdx.x;
    int col = t % DIM, slice = t / DIM;
    float s = 0.f;
    for (int k = slice; k < R1_BLOCKS; k += 10) s += stage1[k * DIM + col];
    sm[t] = s;
    __syncthreads();
    if (t < DIM) {
        float tot = 0.f;
#pragma unroll
        for (int i = 0; i < 10; ++i) tot += sm[i * DIM + t];
        out[t] = tanhf(tot * (1.0f / N_NODES));
    }
}

// ---------------- launch ----------------

extern "C" void kernel_launch(void* const* d_in, const int* in_sizes, int n_in,
                              void* d_out, int out_size, void* d_ws, size_t ws_size,
                              hipStream_t stream) {
    const float* inputs = (const float*)d_in[0];
    const float* W1     = (const float*)d_in[1];
    const float* b1     = (const float*)d_in[2];
    const float* W2     = (const float*)d_in[3];
    const float* b2     = (const float*)d_in[4];
    const float* factor = (const float*)d_in[5];
    const int*   src    = (const int*)d_in[6];
    const int*   dst    = (const int*)d_in[7];
    float* out = (float*)d_out;

    char* ws = (char*)d_ws;
    int*            head     = (int*)(ws + 0);              // 200 KB
    int*            nxt      = (int*)(ws + 262144);         // 3.2 MB
    int*            deg      = (int*)(ws + 3670016);        // 200 KB
    int*            offs     = (int*)(ws + 3932160);        // 200 KB (+1)
    float*          norm     = (float*)(ws + 4194304);      // 200 KB
    int*            partials = (int*)(ws + 4456448);        // 1 KB
    int*            pprefix  = (int*)(ws + 4458496);        // 1 KB
    int2*           entries  = (int2*)(ws + 4718592);       // 6.4 MB
    unsigned short* bufA     = (unsigned short*)(ws + 11534336);  // 9.6 MB bf16 feat
    unsigned short* bufB     = (unsigned short*)(ws + 21364736);  // 9.6 MB bf16 feat
    float*          poolpart = (float*)(ws + 31195136);     // 900 KB (NB_AGG x 96)
    float*          stage1   = (float*)(ws + 32145536);     // 37.6 KB (98 x 96)

    // linked-list CSR build
    hipMemsetAsync(head, 0xFF, N_NODES * sizeof(int), stream);
    link_edges<<<(N_EDGES + 255) / 256, 256, 0, stream>>>(dst, head, nxt);
    walk_count_partials<<<NBLK, SCAN_BLK, 0, stream>>>(head, nxt, deg, norm, partials);
    scan_partials<<<1, SCAN_BLK, 0, stream>>>(partials, pprefix);
    scan_compact<<<NBLK, SCAN_BLK, 0, stream>>>(deg, pprefix, head, nxt, src, factor,
                                                offs, entries);

    const int GEMM_BLOCKS = (N_NODES + MT - 1) / MT;

    // layer 1
    gemm_tiled<float><<<GEMM_BLOCKS, 256, 0, stream>>>(inputs, W1, b1, norm, bufA);
    gather_agg_bf16<true, false><<<NB_AGG, 256, 0, stream>>>(bufA, offs, entries, bufB, nullptr);

    // layer 2 (gather fuses tanh + column pooling, no feature write)
    gemm_tiled<unsigned short><<<GEMM_BLOCKS, 256, 0, stream>>>(bufB, W2, b2, norm, bufA);
    gather_agg_bf16<false, true><<<NB_AGG, 256, 0, stream>>>(bufA, offs, entries, nullptr, poolpart);

    // two-stage pooled reduce -> out
    reduce_stage1<<<R1_BLOCKS, 256, 0, stream>>>(poolpart, stage1);
    reduce_stage2<<<1, 960, 0, stream>>>(stage1, out);
}

// Round 9
// 292.612 us; speedup vs baseline: 1.3236x; 1.0267x over previous
//
#include <hip/hip_runtime.h>
#include <math.h>
#include <type_traits>

#define N_NODES 50000
#define N_EDGES 800000
#define DIM 96
#define BCH 12                    // 16-byte chunks per bf16 row (96 shorts)
#define SCAN_BLK 256
#define NBLK ((N_NODES + SCAN_BLK - 1) / SCAN_BLK)    // 196
#define NPB 21                    // nodes per gather block (21*12 = 252 active threads)
#define NBG ((N_NODES + NPB - 1) / NPB)               // 2381 gather blocks
#define CAP 768                   // LDS entry buffer (int2) per tile
#define R1_ROWS 24
#define R1_BLOCKS ((NBG + R1_ROWS - 1) / R1_ROWS)     // 100

// ---- bf16 helpers (RNE) ----
__device__ __forceinline__ unsigned short f2bf(float f) {
    unsigned int u = __float_as_uint(f);
    u += 0x7FFFu + ((u >> 16) & 1u);
    return (unsigned short)(u >> 16);
}
__device__ __forceinline__ unsigned int pack2bf(float lo, float hi) {
    return (unsigned int)f2bf(lo) | ((unsigned int)f2bf(hi) << 16);
}
__device__ __forceinline__ float bflo(unsigned int u) { return __uint_as_float(u << 16); }
__device__ __forceinline__ float bfhi(unsigned int u) { return __uint_as_float(u & 0xFFFF0000u); }

__device__ __forceinline__ float fast_tanh(float x) {
    float ax = fabsf(x);
    float t = __expf(-2.0f * ax);
    float r = (1.0f - t) / (1.0f + t);
    return copysignf(r, x);
}

__device__ __forceinline__ void acc8(float* a, uint4 v, float f) {
    a[0] += bflo(v.x) * f; a[1] += bfhi(v.x) * f;
    a[2] += bflo(v.y) * f; a[3] += bfhi(v.y) * f;
    a[4] += bflo(v.z) * f; a[5] += bfhi(v.z) * f;
    a[6] += bflo(v.w) * f; a[7] += bfhi(v.w) * f;
}

// ---------------- linked-list CSR build ----------------

__global__ void link_edges(const int* __restrict__ dst, int* __restrict__ head,
                           int* __restrict__ nxt) {
    int e = blockIdx.x * blockDim.x + threadIdx.x;
    if (e >= N_EDGES) return;
    int old = atomicExch(&head[dst[e]], e);
    nxt[e] = old;
}

__global__ void walk_count_partials(const int* __restrict__ head, const int* __restrict__ nxt,
                                    int* __restrict__ deg, float* __restrict__ norm,
                                    int* __restrict__ partials) {
    int b = blockIdx.x, t = threadIdx.x;
    int n = b * SCAN_BLK + t;
    int cnt = 0;
    if (n < N_NODES) {
        int p = head[n];
        while (p >= 0) { ++cnt; p = nxt[p]; }
        deg[n] = cnt;
        norm[n] = rsqrtf(fmaxf((float)cnt, 1.0f));
    }
    int v = cnt;
#pragma unroll
    for (int off = 32; off > 0; off >>= 1) v += __shfl_down(v, off, 64);
    __shared__ int ws[4];
    if ((t & 63) == 0) ws[t >> 6] = v;
    __syncthreads();
    if (t == 0) partials[b] = ws[0] + ws[1] + ws[2] + ws[3];
}

__global__ void scan_partials(const int* __restrict__ partials, int* __restrict__ pprefix) {
    __shared__ int sm[SCAN_BLK];
    int t = threadIdx.x;
    int v = (t < NBLK) ? partials[t] : 0;
    sm[t] = v;
    __syncthreads();
    for (int off = 1; off < SCAN_BLK; off <<= 1) {
        int u = (t >= off) ? sm[t - off] : 0;
        __syncthreads();
        sm[t] += u;
        __syncthreads();
    }
    if (t < NBLK) pprefix[t] = sm[t] - v;
}

__global__ void scan_compact(const int* __restrict__ deg, const int* __restrict__ pprefix,
                             const int* __restrict__ head, const int* __restrict__ nxt,
                             const int* __restrict__ src, const float* __restrict__ factor,
                             int* __restrict__ offs, int2* __restrict__ entries) {
    __shared__ int sm[SCAN_BLK];
    int b = blockIdx.x, t = threadIdx.x;
    int idx = b * SCAN_BLK + t;
    int v = (idx < N_NODES) ? deg[idx] : 0;
    sm[t] = v;
    __syncthreads();
    for (int off = 1; off < SCAN_BLK; off <<= 1) {
        int u = (t >= off) ? sm[t - off] : 0;
        __syncthreads();
        sm[t] += u;
        __syncthreads();
    }
    if (idx < N_NODES) {
        int o = pprefix[b] + sm[t] - v;
        offs[idx] = o;
        int p = head[idx];
        while (p >= 0) {
            entries[o++] = make_int2(src[p], __float_as_int(factor[p]));
            p = nxt[p];
        }
    }
    if (b == 0 && t == 0) offs[N_NODES] = N_EDGES;
}

// ---------------- LDS-tiled GEMM -> bf16 out ----------------

#define MT 64
#define XS_SH 104     // shorts per Xs row (208 B: 16-B aligned)
#define WS_ST 100     // floats per Ws row (400 B: 16-B aligned)

template <typename T>
__global__ void gemm_tiled(const T* __restrict__ X, const float* __restrict__ W,
                           const float* __restrict__ b, const float* __restrict__ norm,
                           unsigned short* __restrict__ out) {
    __shared__ unsigned short Xs[MT * XS_SH];   // 13.3 KB
    __shared__ float Ws[DIM * WS_ST];           // 38.4 KB
    int tid = threadIdx.x;
    int nbase = blockIdx.x * MT;

    if constexpr (std::is_same_v<T, float>) {
#pragma unroll
        for (int it = 0; it < 6; ++it) {
            int idx = tid + 256 * it;
            int row = idx / 24, c = idx % 24;
            int n = nbase + row;
            float4 v = make_float4(0.f, 0.f, 0.f, 0.f);
            if (n < N_NODES) v = ((const float4*)(X + (size_t)n * DIM))[c];
            *((uint2*)&Xs[row * XS_SH + c * 4]) = make_uint2(pack2bf(v.x, v.y), pack2bf(v.z, v.w));
        }
    } else {
#pragma unroll
        for (int it = 0; it < 3; ++it) {
            int idx = tid + 256 * it;
            int row = idx / 12, c = idx % 12;
            int n = nbase + row;
            uint4 v = make_uint4(0, 0, 0, 0);
            if (n < N_NODES) v = ((const uint4*)(X + (size_t)n * DIM))[c];
            *((uint4*)&Xs[row * XS_SH + c * 8]) = v;
        }
    }
#pragma unroll
    for (int it = 0; it < 9; ++it) {
        int idx = tid + 256 * it;
        int row = idx / 24, c = idx % 24;
        *((float4*)&Ws[row * WS_ST + c * 4]) = ((const float4*)(W + (size_t)row * DIM))[c];
    }
    __syncthreads();

    int g = tid & 15;   // col group: j = g*6 + jj
    int r = tid >> 4;   // node group: n = r*4 + i
    float acc[4][6];
#pragma unroll
    for (int i = 0; i < 4; ++i)
#pragma unroll
        for (int jj = 0; jj < 6; ++jj) acc[i][jj] = 0.f;

#pragma unroll 4
    for (int k4 = 0; k4 < 24; ++k4) {
        float xv[4][4];
#pragma unroll
        for (int i = 0; i < 4; ++i) {
            uint2 xw = *(const uint2*)&Xs[(r * 4 + i) * XS_SH + k4 * 4];
            xv[i][0] = bflo(xw.x); xv[i][1] = bfhi(xw.x);
            xv[i][2] = bflo(xw.y); xv[i][3] = bfhi(xw.y);
        }
        float4 wv[6];
#pragma unroll
        for (int jj = 0; jj < 6; ++jj)
            wv[jj] = *(const float4*)&Ws[(g * 6 + jj) * WS_ST + k4 * 4];
#pragma unroll
        for (int i = 0; i < 4; ++i)
#pragma unroll
            for (int jj = 0; jj < 6; ++jj)
                acc[i][jj] += xv[i][0] * wv[jj].x + xv[i][1] * wv[jj].y +
                              xv[i][2] * wv[jj].z + xv[i][3] * wv[jj].w;
    }

#pragma unroll
    for (int i = 0; i < 4; ++i) {
        int n = nbase + r * 4 + i;
        if (n < N_NODES) {
            float nm = norm[n];
            float v0 = (acc[i][0] + b[g * 6 + 0]) * nm;
            float v1 = (acc[i][1] + b[g * 6 + 1]) * nm;
            float v2 = (acc[i][2] + b[g * 6 + 2]) * nm;
            float v3 = (acc[i][3] + b[g * 6 + 3]) * nm;
            float v4 = (acc[i][4] + b[g * 6 + 4]) * nm;
            float v5 = (acc[i][5] + b[g * 6 + 5]) * nm;
            unsigned int* op = (unsigned int*)(out + (size_t)n * DIM + g * 6);
            op[0] = pack2bf(v0, v1);
            op[1] = pack2bf(v2, v3);
            op[2] = pack2bf(v4, v5);
        }
    }
}

// ---------------- gather aggregation: LDS-staged entries, unroll x4 ----------------
// Block = 21 nodes x 12 chunks (252 active threads). Entries for the block's
// contiguous edge range are staged into LDS once (tiled for safety), then the
// inner loop reads addresses from LDS and keeps 4 feat loads in flight.
// POOL=true (layer 2): tanh + accumulate into 96-col LDS pool, one partial
// vector per block (no feature write, no global atomics).

template <bool DO_TANH, bool POOL>
__global__ void gather_agg_bf16(const unsigned short* __restrict__ feat,
                                const int* __restrict__ offs,
                                const int2* __restrict__ entries,
                                unsigned short* __restrict__ out,
                                float* __restrict__ partials) {
    __shared__ int2 ents[CAP];       // 6 KB
    __shared__ float pool[DIM];
    __shared__ int sh_base, sh_cnt;
    int tid = threadIdx.x;
    int n0 = blockIdx.x * NPB;
    int n1 = min(n0 + NPB, N_NODES);
    if (POOL && tid < DIM) pool[tid] = 0.f;
    if (tid == 0) { sh_base = offs[n0]; sh_cnt = offs[n1] - sh_base; }
    __syncthreads();
    int base = sh_base, cnt = sh_cnt;

    int nl = tid / BCH;              // local node 0..20
    int c  = tid - nl * BCH;         // chunk 0..11
    int n  = n0 + nl;
    bool active = (tid < NPB * BCH) && (n < N_NODES);
    int lb = 0, le = 0;
    if (active) { lb = offs[n] - base; le = offs[n + 1] - base; }

    float a0[8], a1[8];
#pragma unroll
    for (int i = 0; i < 8; ++i) { a0[i] = 0.f; a1[i] = 0.f; }

    for (int tb = 0; tb < cnt; tb += CAP) {
        int tcnt = min(cnt - tb, CAP);
        if (tb) __syncthreads();                 // protect ents reuse
        for (int i = tid; i < tcnt; i += 256) ents[i] = entries[base + tb + i];
        __syncthreads();
        int s = max(lb - tb, 0), e = min(le - tb, tcnt);
        int p = s;
        for (; p + 3 < e; p += 4) {
            int2 e0 = ents[p], e1 = ents[p + 1], e2 = ents[p + 2], e3 = ents[p + 3];
            uint4 v0 = *((const uint4*)(feat + (size_t)e0.x * DIM) + c);
            uint4 v1 = *((const uint4*)(feat + (size_t)e1.x * DIM) + c);
            uint4 v2 = *((const uint4*)(feat + (size_t)e2.x * DIM) + c);
            uint4 v3 = *((const uint4*)(feat + (size_t)e3.x * DIM) + c);
            acc8(a0, v0, __int_as_float(e0.y));
            acc8(a1, v1, __int_as_float(e1.y));
            acc8(a0, v2, __int_as_float(e2.y));
            acc8(a1, v3, __int_as_float(e3.y));
        }
        for (; p < e; ++p) {
            int2 e0 = ents[p];
            uint4 v0 = *((const uint4*)(feat + (size_t)e0.x * DIM) + c);
            acc8(a0, v0, __int_as_float(e0.y));
        }
    }

#pragma unroll
    for (int i = 0; i < 8; ++i) a0[i] += a1[i];
    if (DO_TANH || POOL) {
#pragma unroll
        for (int i = 0; i < 8; ++i) a0[i] = fast_tanh(a0[i]);
    }
    if (!POOL) {
        if (active) {
            uint4 o;
            o.x = pack2bf(a0[0], a0[1]);
            o.y = pack2bf(a0[2], a0[3]);
            o.z = pack2bf(a0[4], a0[5]);
            o.w = pack2bf(a0[6], a0[7]);
            ((uint4*)out)[n * BCH + c] = o;
        }
    } else {
        if (active) {
#pragma unroll
            for (int i = 0; i < 8; ++i) atomicAdd(&pool[c * 8 + i], a0[i]);
        }
        __syncthreads();
        if (tid < DIM) partials[(size_t)blockIdx.x * DIM + tid] = pool[tid];
    }
}

// ---------------- two-stage pooled reduce ----------------

__global__ void reduce_stage1(const float* __restrict__ poolpart, float* __restrict__ stage1) {
    __shared__ float pool[DIM];
    int b = blockIdx.x, t = threadIdx.x;
    if (t < DIM) pool[t] = 0.f;
    __syncthreads();
    const int base = b * R1_ROWS * DIM;
    float loc = 0.f;
    int lastc = -1;
    for (int i = t; i < R1_ROWS * DIM; i += 256) {
        int gi = base + i;
        if (gi < NBG * DIM) {
            int col = i % DIM;
            if (col != lastc) {
                if (lastc >= 0) atomicAdd(&pool[lastc], loc);
                lastc = col; loc = 0.f;
            }
            loc += poolpart[gi];
        }
    }
    if (lastc >= 0) atomicAdd(&pool[lastc], loc);
    __syncthreads();
    if (t < DIM) stage1[b * DIM + t] = pool[t];
}

__global__ void reduce_stage2(const float* __restrict__ stage1, float* __restrict__ out) {
    __shared__ float sm[960];
    int t = threadIdx.x;
    int col = t % DIM, slice = t / DIM;
    float s = 0.f;
    for (int k = slice; k < R1_BLOCKS; k += 10) s += stage1[k * DIM + col];
    sm[t] = s;
    __syncthreads();
    if (t < DIM) {
        float tot = 0.f;
#pragma unroll
        for (int i = 0; i < 10; ++i) tot += sm[i * DIM + t];
        out[t] = tanhf(tot * (1.0f / N_NODES));
    }
}

// ---------------- launch ----------------

extern "C" void kernel_launch(void* const* d_in, const int* in_sizes, int n_in,
                              void* d_out, int out_size, void* d_ws, size_t ws_size,
                              hipStream_t stream) {
    const float* inputs = (const float*)d_in[0];
    const float* W1     = (const float*)d_in[1];
    const float* b1     = (const float*)d_in[2];
    const float* W2     = (const float*)d_in[3];
    const float* b2     = (const float*)d_in[4];
    const float* factor = (const float*)d_in[5];
    const int*   src    = (const int*)d_in[6];
    const int*   dst    = (const int*)d_in[7];
    float* out = (float*)d_out;

    char* ws = (char*)d_ws;
    int*            head     = (int*)(ws + 0);              // 200 KB
    int*            nxt      = (int*)(ws + 262144);         // 3.2 MB
    int*            deg      = (int*)(ws + 3670016);        // 200 KB
    int*            offs     = (int*)(ws + 3932160);        // 200 KB (+1)
    float*          norm     = (float*)(ws + 4194304);      // 200 KB
    int*            partials = (int*)(ws + 4456448);        // 1 KB
    int*            pprefix  = (int*)(ws + 4458496);        // 1 KB
    int2*           entries  = (int2*)(ws + 4718592);       // 6.4 MB
    unsigned short* bufA     = (unsigned short*)(ws + 11534336);  // 9.6 MB bf16 feat
    unsigned short* bufB     = (unsigned short*)(ws + 21364736);  // 9.6 MB bf16 feat
    float*          poolpart = (float*)(ws + 31195136);     // 914 KB (NBG x 96)
    float*          stage1   = (float*)(ws + 32145536);     // 38.4 KB (100 x 96)

    // linked-list CSR build
    hipMemsetAsync(head, 0xFF, N_NODES * sizeof(int), stream);
    link_edges<<<(N_EDGES + 255) / 256, 256, 0, stream>>>(dst, head, nxt);
    walk_count_partials<<<NBLK, SCAN_BLK, 0, stream>>>(head, nxt, deg, norm, partials);
    scan_partials<<<1, SCAN_BLK, 0, stream>>>(partials, pprefix);
    scan_compact<<<NBLK, SCAN_BLK, 0, stream>>>(deg, pprefix, head, nxt, src, factor,
                                                offs, entries);

    const int GEMM_BLOCKS = (N_NODES + MT - 1) / MT;

    // layer 1
    gemm_tiled<float><<<GEMM_BLOCKS, 256, 0, stream>>>(inputs, W1, b1, norm, bufA);
    gather_agg_bf16<true, false><<<NBG, 256, 0, stream>>>(bufA, offs, entries, bufB, nullptr);

    // layer 2 (gather fuses tanh + column pooling, no feature write)
    gemm_tiled<unsigned short><<<GEMM_BLOCKS, 256, 0, stream>>>(bufB, W2, b2, norm, bufA);
    gather_agg_bf16<false, true><<<NBG, 256, 0, stream>>>(bufA, offs, entries, nullptr, poolpart);

    // two-stage pooled reduce -> out
    reduce_stage1<<<R1_BLOCKS, 256, 0, stream>>>(poolpart, stage1);
    reduce_stage2<<<1, 960, 0, stream>>>(stage1, out);
}

// Round 10
// 265.035 us; speedup vs baseline: 1.4613x; 1.1041x over previous
//
#include <hip/hip_runtime.h>
#include <math.h>
#include <type_traits>

#define N_NODES 50000
#define N_EDGES 800000
#define DIM 96
#define BCH 12                    // 16-byte chunks per bf16 row (96 shorts)
#define SCAN_BLK 256
#define NBLK ((N_NODES + SCAN_BLK - 1) / SCAN_BLK)    // 196
#define NPB 21                    // nodes per gather block (21*12 = 252 active threads)
#define NBG ((N_NODES + NPB - 1) / NPB)               // 2381 gather blocks
#define CAP 768                   // LDS entry buffer (int2) per tile
#define R1_ROWS 24
#define R1_BLOCKS ((NBG + R1_ROWS - 1) / R1_ROWS)     // 100

typedef short v8s __attribute__((ext_vector_type(8)));   // 8 bf16 = 4 VGPRs
typedef float v4f __attribute__((ext_vector_type(4)));   // MFMA accumulator

// ---- bf16 helpers (RNE) ----
__device__ __forceinline__ unsigned short f2bf(float f) {
    unsigned int u = __float_as_uint(f);
    u += 0x7FFFu + ((u >> 16) & 1u);
    return (unsigned short)(u >> 16);
}
__device__ __forceinline__ unsigned int pack2bf(float lo, float hi) {
    return (unsigned int)f2bf(lo) | ((unsigned int)f2bf(hi) << 16);
}
__device__ __forceinline__ float bflo(unsigned int u) { return __uint_as_float(u << 16); }
__device__ __forceinline__ float bfhi(unsigned int u) { return __uint_as_float(u & 0xFFFF0000u); }

__device__ __forceinline__ float fast_tanh(float x) {
    float ax = fabsf(x);
    float t = __expf(-2.0f * ax);
    float r = (1.0f - t) / (1.0f + t);
    return copysignf(r, x);
}

__device__ __forceinline__ void acc8(float* a, uint4 v, float f) {
    a[0] += bflo(v.x) * f; a[1] += bfhi(v.x) * f;
    a[2] += bflo(v.y) * f; a[3] += bfhi(v.y) * f;
    a[4] += bflo(v.z) * f; a[5] += bfhi(v.z) * f;
    a[6] += bflo(v.w) * f; a[7] += bfhi(v.w) * f;
}

union U4S8 { uint4 u; v8s s; };

// ---------------- linked-list CSR build ----------------

__global__ void link_edges(const int* __restrict__ dst, int* __restrict__ head,
                           int* __restrict__ nxt) {
    int e = blockIdx.x * blockDim.x + threadIdx.x;
    if (e >= N_EDGES) return;
    int old = atomicExch(&head[dst[e]], e);
    nxt[e] = old;
}

__global__ void walk_count_partials(const int* __restrict__ head, const int* __restrict__ nxt,
                                    int* __restrict__ deg, float* __restrict__ norm,
                                    int* __restrict__ partials) {
    int b = blockIdx.x, t = threadIdx.x;
    int n = b * SCAN_BLK + t;
    int cnt = 0;
    if (n < N_NODES) {
        int p = head[n];
        while (p >= 0) { ++cnt; p = nxt[p]; }
        deg[n] = cnt;
        norm[n] = rsqrtf(fmaxf((float)cnt, 1.0f));
    }
    int v = cnt;
#pragma unroll
    for (int off = 32; off > 0; off >>= 1) v += __shfl_down(v, off, 64);
    __shared__ int ws[4];
    if ((t & 63) == 0) ws[t >> 6] = v;
    __syncthreads();
    if (t == 0) partials[b] = ws[0] + ws[1] + ws[2] + ws[3];
}

__global__ void scan_partials(const int* __restrict__ partials, int* __restrict__ pprefix) {
    __shared__ int sm[SCAN_BLK];
    int t = threadIdx.x;
    int v = (t < NBLK) ? partials[t] : 0;
    sm[t] = v;
    __syncthreads();
    for (int off = 1; off < SCAN_BLK; off <<= 1) {
        int u = (t >= off) ? sm[t - off] : 0;
        __syncthreads();
        sm[t] += u;
        __syncthreads();
    }
    if (t < NBLK) pprefix[t] = sm[t] - v;
}

__global__ void scan_compact(const int* __restrict__ deg, const int* __restrict__ pprefix,
                             const int* __restrict__ head, const int* __restrict__ nxt,
                             const int* __restrict__ src, const float* __restrict__ factor,
                             int* __restrict__ offs, int2* __restrict__ entries) {
    __shared__ int sm[SCAN_BLK];
    int b = blockIdx.x, t = threadIdx.x;
    int idx = b * SCAN_BLK + t;
    int v = (idx < N_NODES) ? deg[idx] : 0;
    sm[t] = v;
    __syncthreads();
    for (int off = 1; off < SCAN_BLK; off <<= 1) {
        int u = (t >= off) ? sm[t - off] : 0;
        __syncthreads();
        sm[t] += u;
        __syncthreads();
    }
    if (idx < N_NODES) {
        int o = pprefix[b] + sm[t] - v;
        offs[idx] = o;
        int p = head[idx];
        while (p >= 0) {
            entries[o++] = make_int2(src[p], __float_as_int(factor[p]));
            p = nxt[p];
        }
    }
    if (b == 0 && t == 0) offs[N_NODES] = N_EDGES;
}

// ---------------- W pre-swizzle: B-fragments for mfma_f32_16x16x32_bf16 ----------------
// B[k][n] lane layout: lane holds B[k = (lane>>4)*8 + i][n = lane&15], i=0..7.
// B[k][j] = W[j][k]  ->  lane reads W[jt*16 + (lane&15)][kt*32 + (lane>>4)*8 .. +7]
// (8 consecutive fp32), packs to 8 bf16, stores at linear frag position.

__global__ void swizzle_W(const float* __restrict__ W, uint4* __restrict__ bsw) {
    int idx = blockIdx.x * blockDim.x + threadIdx.x;
    if (idx >= 18 * 64) return;
    int t = idx >> 6, lane = idx & 63;
    int kt = t / 6, jt = t % 6;
    int quad = lane >> 4, l16 = lane & 15;
    const float4* wp = (const float4*)(W + (size_t)(jt * 16 + l16) * DIM + kt * 32 + quad * 8);
    float4 w0 = wp[0], w1 = wp[1];
    bsw[idx] = make_uint4(pack2bf(w0.x, w0.y), pack2bf(w0.z, w0.w),
                          pack2bf(w1.x, w1.y), pack2bf(w1.z, w1.w));
}

// ---------------- MFMA GEMM:  out[n][j] = bf16((X@W^T + b)[n][j] * norm[n]) ----------------
// Block = 4 waves x 16 nodes. Wave: acc = 6 j-tiles of 16x16; K = 3 tiles of 32.
// A-frag: lane holds X[n0+(lane&15)][kt*32 + quad*8 .. +7] (one 16B load).
// Epilogue via per-wave LDS tile -> contiguous uint4 stores.

#define TILE_SH 104   // shorts per LDS tile row

template <typename T>
__global__ __launch_bounds__(256) void gemm_mfma(const T* __restrict__ X,
                                                 const uint4* __restrict__ bsw,
                                                 const float* __restrict__ bias,
                                                 const float* __restrict__ norm,
                                                 unsigned short* __restrict__ out) {
    __shared__ unsigned short tile[4][16 * TILE_SH];   // 13.3 KB
    int tid = threadIdx.x;
    int wave = tid >> 6, lane = tid & 63;
    int quad = lane >> 4, l16 = lane & 15;
    int n0 = blockIdx.x * 64 + wave * 16;
    int rowc = min(n0 + l16, N_NODES - 1);

    // preload all 18 B-fragments (L1-hot: same addresses for every wave/block)
    uint4 bfr[18];
#pragma unroll
    for (int t = 0; t < 18; ++t) bfr[t] = bsw[t * 64 + lane];

    v4f acc[6];
#pragma unroll
    for (int jt = 0; jt < 6; ++jt) acc[jt] = (v4f)(0.0f);

#pragma unroll
    for (int kt = 0; kt < 3; ++kt) {
        U4S8 a;
        if constexpr (std::is_same_v<T, float>) {
            const float4* xp = (const float4*)(X + (size_t)rowc * DIM + kt * 32 + quad * 8);
            float4 x0 = xp[0], x1 = xp[1];
            a.u = make_uint4(pack2bf(x0.x, x0.y), pack2bf(x0.z, x0.w),
                             pack2bf(x1.x, x1.y), pack2bf(x1.z, x1.w));
        } else {
            a.u = *(const uint4*)(X + (size_t)rowc * DIM + kt * 32 + quad * 8);
        }
#pragma unroll
        for (int jt = 0; jt < 6; ++jt) {
            U4S8 bb; bb.u = bfr[kt * 6 + jt];
            acc[jt] = __builtin_amdgcn_mfma_f32_16x16x32_bf16(a.s, bb.s, acc[jt], 0, 0, 0);
        }
    }

    // epilogue: C/D lane layout col=lane&15, row=quad*4+reg
    float nm[4];
#pragma unroll
    for (int r = 0; r < 4; ++r) nm[r] = norm[min(n0 + quad * 4 + r, N_NODES - 1)];
#pragma unroll
    for (int jt = 0; jt < 6; ++jt) {
        float bj = bias[jt * 16 + l16];
#pragma unroll
        for (int r = 0; r < 4; ++r) {
            float v = (acc[jt][r] + bj) * nm[r];
            tile[wave][(quad * 4 + r) * TILE_SH + jt * 16 + l16] = f2bf(v);
        }
    }
    // wave-local LDS round-trip (no cross-wave sharing; compiler inserts lgkmcnt waits)
    __builtin_amdgcn_s_waitcnt(0);   // conservative: drain lgkm before reads
#pragma unroll
    for (int i = 0; i < 3; ++i) {
        int chunk = lane + 64 * i;        // 0..191 = 16 rows x 12 uint4
        int rr = chunk / 12, cc = chunk - rr * 12;
        int gn = n0 + rr;
        if (gn < N_NODES) {
            uint4 v = *(uint4*)&tile[wave][rr * TILE_SH + cc * 8];
            *(uint4*)(out + (size_t)gn * DIM + cc * 8) = v;
        }
    }
}

// ---------------- gather aggregation: LDS-staged entries, unroll x4 ----------------

template <bool DO_TANH, bool POOL>
__global__ void gather_agg_bf16(const unsigned short* __restrict__ feat,
                                const int* __restrict__ offs,
                                const int2* __restrict__ entries,
                                unsigned short* __restrict__ out,
                                float* __restrict__ partials) {
    __shared__ int2 ents[CAP];       // 6 KB
    __shared__ float pool[DIM];
    __shared__ int sh_base, sh_cnt;
    int tid = threadIdx.x;
    int n0 = blockIdx.x * NPB;
    int n1 = min(n0 + NPB, N_NODES);
    if (POOL && tid < DIM) pool[tid] = 0.f;
    if (tid == 0) { sh_base = offs[n0]; sh_cnt = offs[n1] - sh_base; }
    __syncthreads();
    int base = sh_base, cnt = sh_cnt;

    int nl = tid / BCH;
    int c  = tid - nl * BCH;
    int n  = n0 + nl;
    bool active = (tid < NPB * BCH) && (n < N_NODES);
    int lb = 0, le = 0;
    if (active) { lb = offs[n] - base; le = offs[n + 1] - base; }

    float a0[8], a1[8];
#pragma unroll
    for (int i = 0; i < 8; ++i) { a0[i] = 0.f; a1[i] = 0.f; }

    for (int tb = 0; tb < cnt; tb += CAP) {
        int tcnt = min(cnt - tb, CAP);
        if (tb) __syncthreads();
        for (int i = tid; i < tcnt; i += 256) ents[i] = entries[base + tb + i];
        __syncthreads();
        int s = max(lb - tb, 0), e = min(le - tb, tcnt);
        int p = s;
        for (; p + 3 < e; p += 4) {
            int2 e0 = ents[p], e1 = ents[p + 1], e2 = ents[p + 2], e3 = ents[p + 3];
            uint4 v0 = *((const uint4*)(feat + (size_t)e0.x * DIM) + c);
            uint4 v1 = *((const uint4*)(feat + (size_t)e1.x * DIM) + c);
            uint4 v2 = *((const uint4*)(feat + (size_t)e2.x * DIM) + c);
            uint4 v3 = *((const uint4*)(feat + (size_t)e3.x * DIM) + c);
            acc8(a0, v0, __int_as_float(e0.y));
            acc8(a1, v1, __int_as_float(e1.y));
            acc8(a0, v2, __int_as_float(e2.y));
            acc8(a1, v3, __int_as_float(e3.y));
        }
        for (; p < e; ++p) {
            int2 e0 = ents[p];
            uint4 v0 = *((const uint4*)(feat + (size_t)e0.x * DIM) + c);
            acc8(a0, v0, __int_as_float(e0.y));
        }
    }

#pragma unroll
    for (int i = 0; i < 8; ++i) a0[i] += a1[i];
    if (DO_TANH || POOL) {
#pragma unroll
        for (int i = 0; i < 8; ++i) a0[i] = fast_tanh(a0[i]);
    }
    if (!POOL) {
        if (active) {
            uint4 o;
            o.x = pack2bf(a0[0], a0[1]);
            o.y = pack2bf(a0[2], a0[3]);
            o.z = pack2bf(a0[4], a0[5]);
            o.w = pack2bf(a0[6], a0[7]);
            ((uint4*)out)[n * BCH + c] = o;
        }
    } else {
        if (active) {
#pragma unroll
            for (int i = 0; i < 8; ++i) atomicAdd(&pool[c * 8 + i], a0[i]);
        }
        __syncthreads();
        if (tid < DIM) partials[(size_t)blockIdx.x * DIM + tid] = pool[tid];
    }
}

// ---------------- two-stage pooled reduce ----------------

__global__ void reduce_stage1(const float* __restrict__ poolpart, float* __restrict__ stage1) {
    __shared__ float pool[DIM];
    int b = blockIdx.x, t = threadIdx.x;
    if (t < DIM) pool[t] = 0.f;
    __syncthreads();
    const int base = b * R1_ROWS * DIM;
    float loc = 0.f;
    int lastc = -1;
    for (int i = t; i < R1_ROWS * DIM; i += 256) {
        int gi = base + i;
        if (gi < NBG * DIM) {
            int col = i % DIM;
            if (col != lastc) {
                if (lastc >= 0) atomicAdd(&pool[lastc], loc);
                lastc = col; loc = 0.f;
            }
            loc += poolpart[gi];
        }
    }
    if (lastc >= 0) atomicAdd(&pool[lastc], loc);
    __syncthreads();
    if (t < DIM) stage1[b * DIM + t] = pool[t];
}

__global__ void reduce_stage2(const float* __restrict__ stage1, float* __restrict__ out) {
    __shared__ float sm[960];
    int t = threadIdx.x;
    int col = t % DIM, slice = t / DIM;
    float s = 0.f;
    for (int k = slice; k < R1_BLOCKS; k += 10) s += stage1[k * DIM + col];
    sm[t] = s;
    __syncthreads();
    if (t < DIM) {
        float tot = 0.f;
#pragma unroll
        for (int i = 0; i < 10; ++i) tot += sm[i * DIM + t];
        out[t] = tanhf(tot * (1.0f / N_NODES));
    }
}

// ---------------- launch ----------------

extern "C" void kernel_launch(void* const* d_in, const int* in_sizes, int n_in,
                              void* d_out, int out_size, void* d_ws, size_t ws_size,
                              hipStream_t stream) {
    const float* inputs = (const float*)d_in[0];
    const float* W1     = (const float*)d_in[1];
    const float* b1     = (const float*)d_in[2];
    const float* W2     = (const float*)d_in[3];
    const float* b2     = (const float*)d_in[4];
    const float* factor = (const float*)d_in[5];
    const int*   src    = (const int*)d_in[6];
    const int*   dst    = (const int*)d_in[7];
    float* out = (float*)d_out;

    char* ws = (char*)d_ws;
    int*            head     = (int*)(ws + 0);              // 200 KB
    int*            nxt      = (int*)(ws + 262144);         // 3.2 MB
    int*            deg      = (int*)(ws + 3670016);        // 200 KB
    int*            offs     = (int*)(ws + 3932160);        // 200 KB (+1)
    float*          norm     = (float*)(ws + 4194304);      // 200 KB
    int*            partials = (int*)(ws + 4456448);        // 1 KB
    int*            pprefix  = (int*)(ws + 4458496);        // 1 KB
    int2*           entries  = (int2*)(ws + 4718592);       // 6.4 MB
    unsigned short* bufA     = (unsigned short*)(ws + 11534336);  // 9.6 MB bf16 feat
    unsigned short* bufB     = (unsigned short*)(ws + 21364736);  // 9.6 MB bf16 feat
    float*          poolpart = (float*)(ws + 31195136);     // 914 KB (NBG x 96)
    float*          stage1   = (float*)(ws + 32145536);     // 38.4 KB
    uint4*          bsw1     = (uint4*)(ws + 33554432);     // 18 KB W1 fragments
    uint4*          bsw2     = (uint4*)(ws + 33574912);     // 18 KB W2 fragments

    // W fragment pre-swizzle (independent of CSR build)
    swizzle_W<<<5, 256, 0, stream>>>(W1, bsw1);
    swizzle_W<<<5, 256, 0, stream>>>(W2, bsw2);

    // linked-list CSR build
    hipMemsetAsync(head, 0xFF, N_NODES * sizeof(int), stream);
    link_edges<<<(N_EDGES + 255) / 256, 256, 0, stream>>>(dst, head, nxt);
    walk_count_partials<<<NBLK, SCAN_BLK, 0, stream>>>(head, nxt, deg, norm, partials);
    scan_partials<<<1, SCAN_BLK, 0, stream>>>(partials, pprefix);
    scan_compact<<<NBLK, SCAN_BLK, 0, stream>>>(deg, pprefix, head, nxt, src, factor,
                                                offs, entries);

    const int GEMM_BLOCKS = (N_NODES + 63) / 64;   // 782

    // layer 1
    gemm_mfma<float><<<GEMM_BLOCKS, 256, 0, stream>>>(inputs, bsw1, b1, norm, bufA);
    gather_agg_bf16<true, false><<<NBG, 256, 0, stream>>>(bufA, offs, entries, bufB, nullptr);

    // layer 2 (gather fuses tanh + column pooling, no feature write)
    gemm_mfma<unsigned short><<<GEMM_BLOCKS, 256, 0, stream>>>(bufB, bsw2, b2, norm, bufA);
    gather_agg_bf16<false, true><<<NBG, 256, 0, stream>>>(bufA, offs, entries, nullptr, poolpart);

    // two-stage pooled reduce -> out
    reduce_stage1<<<R1_BLOCKS, 256, 0, stream>>>(poolpart, stage1);
    reduce_stage2<<<1, 960, 0, stream>>>(stage1, out);
}